// Round 11
// baseline (295.976 us; speedup 1.0000x reference)
//
#include <hip/hip_runtime.h>
#include <stdint.h>

typedef __attribute__((ext_vector_type(8))) short bf16x8;
typedef __attribute__((ext_vector_type(4))) float f32x4;

constexpr int kSEQ = 2048;   // 1 + 2047
constexpr int kD   = 256;
constexpr int kHD  = 32;
constexpr int kFF  = 1024;
constexpr int kA   = 16;

__device__ __forceinline__ unsigned short f2b(float f) {
  union { float f; unsigned int u; } v; v.f = f;
  unsigned int r = v.u + 0x7FFFu + ((v.u >> 16) & 1u);
  return (unsigned short)(r >> 16);
}

struct ConvTable {
  const float* src[13];
  int K[13];
  int N[13];
  int dst[13];
  int tstart[14];
};

union SharedU {
  struct { unsigned short lt[64][72]; } cv;
  struct { unsigned short Al[64][40]; unsigned short Bl[32][40]; } g64;
  struct { unsigned short Kl[64][40]; unsigned short Vt[32][72];
           unsigned short Pl[4][16][72]; } at;
};

struct MegaParams {
  ConvTable tab;
  const float *obs, *oldv, *Wcore, *bcore, *Wmemo0, *bmemo, *Wmemo2;
  const float *bq, *bk, *bv, *bo, *ln1g, *ln1b, *ln2g, *ln2b, *bff1, *bff2;
  const float *aW1, *ab1, *aW2, *ab2, *aWo, *abo;
  const float *cW1, *cb1, *cW2, *cb2, *cWo, *cbo;
  float* xf; unsigned short* xb;
  unsigned short *qb, *kb, *vb, *wT;
  float *pacc, *pml, *h1, *h2, *out;
  int oQKV[2], oWoT[2], oFF1[2], oFF2[2];
  int convJobs, nsplit, tpb;
};

// ---------------------------------------------------------------- conv job
__device__ void conv_job(const MegaParams& p, SharedU& sh, int job) {
  const int tid = threadIdx.x;
  if (job == p.convJobs) {  // row-0 embed
    float a = p.bcore[tid];
    #pragma unroll 8
    for (int k = 0; k < 256; k++) a += p.obs[k] * p.Wcore[k * kD + tid];
    p.xf[tid] = a;
    p.xb[tid] = f2b(a);
    return;
  }
  int m = 0;
  while (job >= p.tab.tstart[m + 1]) m++;
  const int tloc = job - p.tab.tstart[m];
  const int N = p.tab.N[m], K = p.tab.K[m];
  const int ntile = N >> 6;
  const int k0 = (tloc / ntile) * 64, n0 = (tloc % ntile) * 64;
  const float* src = p.tab.src[m];
  {
    const int r = tid >> 2, c16 = (tid & 3) * 16;
    const float* sp = src + (size_t)(k0 + r) * N + n0 + c16;
    #pragma unroll
    for (int j = 0; j < 16; j++) sh.cv.lt[r][c16 + j] = f2b(sp[j]);
  }
  __syncthreads();
  {
    const int n = tid >> 2, kc = (tid & 3) * 16;
    unsigned short* dp = p.wT + p.tab.dst[m] + (size_t)(n0 + n) * K + k0 + kc;
    unsigned short g[16];
    #pragma unroll
    for (int j = 0; j < 16; j++) g[j] = sh.cv.lt[kc + j][n];
    *(bf16x8*)dp = *(bf16x8*)&g[0];
    *(bf16x8*)(dp + 8) = *(bf16x8*)&g[8];
  }
}

// ---------------------------------------------------------------- memo job
__device__ void memo_job(const MegaParams& p, SharedU& sh, int job) {
  const int tid = threadIdx.x;
  const int w = tid >> 6, l = tid & 63, lg = l >> 4, lr = l & 15;
  const int sr = tid >> 2, sk = (tid & 3) * 8;
  const int kr = tid >> 3, nc = (tid & 7) * 4;
  const int m0 = (job & 31) * 64, n0 = (job >> 5) * 32;
  f32x4 acc[2];
  #pragma unroll
  for (int c = 0; c < 2; c++)
    #pragma unroll
    for (int i = 0; i < 4; i++) acc[c][i] = 0.f;

  auto loadA = [&](int k0) -> bf16x8 {
    bf16x8 av;
    if (m0 + sr < 2047) {
      const float* ap = p.oldv + (size_t)(m0 + sr) * 256 + k0 + sk;
      #pragma unroll
      for (int j = 0; j < 8; j++) av[j] = (short)f2b(ap[j]);
    } else {
      #pragma unroll
      for (int j = 0; j < 8; j++) av[j] = 0;
    }
    return av;
  };
  auto loadB = [&](int k0, float* b4) {
    const float* bp = p.Wmemo0 + (size_t)(k0 + kr) * kD + n0 + nc;
    #pragma unroll
    for (int j = 0; j < 4; j++) b4[j] = bp[j];
  };

  bf16x8 av = loadA(0);
  float b4[4];
  loadB(0, b4);

  for (int k0 = 0; k0 < 256; k0 += 32) {
    __syncthreads();
    *(bf16x8*)&sh.g64.Al[sr][sk] = av;
    #pragma unroll
    for (int j = 0; j < 4; j++) sh.g64.Bl[nc + j][kr] = f2b(b4[j]);
    __syncthreads();
    if (k0 + 32 < 256) {
      av = loadA(k0 + 32);
      loadB(k0 + 32, b4);
    }
    bf16x8 af = *(bf16x8*)&sh.g64.Al[w * 16 + lr][8 * lg];
    #pragma unroll
    for (int c = 0; c < 2; c++) {
      bf16x8 bf = *(bf16x8*)&sh.g64.Bl[c * 16 + lr][8 * lg];
      acc[c] = __builtin_amdgcn_mfma_f32_16x16x32_bf16(af, bf, acc[c], 0, 0, 0);
    }
  }

  #pragma unroll
  for (int c = 0; c < 2; c++)
    #pragma unroll
    for (int i = 0; i < 4; i++) {
      const int gr = m0 + w * 16 + 4 * lg + i;
      const int gc = n0 + c * 16 + lr;
      if (gr >= 2047) continue;
      const float v = acc[c][i] + p.bmemo[gc] + p.Wmemo2[(size_t)gr * kD + gc];
      p.xf[(size_t)(gr + 1) * kD + gc] = v;
      p.xb[(size_t)(gr + 1) * kD + gc] = f2b(v);
    }
}

__global__ __launch_bounds__(256) void k_cvm(MegaParams p) {
  __shared__ SharedU sh;
  if (blockIdx.x < 256) memo_job(p, sh, blockIdx.x);
  else conv_job(p, sh, blockIdx.x - 256);
}

// ---------------------------------------------------------------- qkv GEMM (layer 0)
__global__ __launch_bounds__(256) void k_qkv(MegaParams p, int lyr) {
  __shared__ SharedU sh;
  const int tid = threadIdx.x;
  const int w = tid >> 6, l = tid & 63, lg = l >> 4, lr = l & 15;
  const int sr = tid >> 2, sk = (tid & 3) * 8;
  const int job = blockIdx.x;
  const int m0 = (job & 31) * 64, n0 = (job >> 5) * 32;
  const unsigned short* BT = p.wT + p.oQKV[lyr];
  f32x4 acc[2];
  #pragma unroll
  for (int c = 0; c < 2; c++)
    #pragma unroll
    for (int i = 0; i < 4; i++) acc[c][i] = 0.f;

  bf16x8 av = *(const bf16x8*)(p.xb + (size_t)(m0 + sr) * 256 + sk);
  bf16x8 bv;
  if (tid < 128) bv = *(const bf16x8*)(BT + (size_t)(n0 + sr) * 256 + sk);

  for (int k0 = 0; k0 < 256; k0 += 32) {
    __syncthreads();
    *(bf16x8*)&sh.g64.Al[sr][sk] = av;
    if (tid < 128) *(bf16x8*)&sh.g64.Bl[sr][sk] = bv;
    __syncthreads();
    if (k0 + 32 < 256) {
      av = *(const bf16x8*)(p.xb + (size_t)(m0 + sr) * 256 + k0 + 32 + sk);
      if (tid < 128)
        bv = *(const bf16x8*)(BT + (size_t)(n0 + sr) * 256 + k0 + 32 + sk);
    }
    bf16x8 af = *(bf16x8*)&sh.g64.Al[w * 16 + lr][8 * lg];
    #pragma unroll
    for (int c = 0; c < 2; c++) {
      bf16x8 bf = *(bf16x8*)&sh.g64.Bl[c * 16 + lr][8 * lg];
      acc[c] = __builtin_amdgcn_mfma_f32_16x16x32_bf16(af, bf, acc[c], 0, 0, 0);
    }
  }

  #pragma unroll
  for (int c = 0; c < 2; c++)
    #pragma unroll
    for (int i = 0; i < 4; i++) {
      const int gr = m0 + w * 16 + 4 * lg + i;
      const int gc = n0 + c * 16 + lr;
      const int t = gc >> 8, cc = gc & 255;
      const float* bp = (t == 0) ? (p.bq + lyr * 256)
                        : (t == 1 ? (p.bk + lyr * 256) : (p.bv + lyr * 256));
      unsigned short* op = (t == 0) ? p.qb : (t == 1 ? p.kb : p.vb);
      float v = acc[c][i] + bp[cc];
      if (t == 0) v *= 0.17677669529663687f;
      op[(size_t)gr * kD + cc] = f2b(v);
    }
}

// ---------------------------------------------------------------- attention
__device__ void attn_job(SharedU& sh, int qb_, int h, int s, int tpb,
                         const unsigned short* q, const unsigned short* k,
                         const unsigned short* v, float* pacc, float* pml) {
  const int tid = threadIdx.x;
  const int w = tid >> 6, l = tid & 63, lg = l >> 4, lr = l & 15;
  const int q0 = qb_ * 64;
  const int hoff = h * kHD;
  const int sr = tid >> 2, sk = (tid & 3) * 8;
  const int t0 = s * tpb;

  const bf16x8 qf =
      *(const bf16x8*)(q + (size_t)(q0 + w * 16 + lr) * kD + hoff + 8 * lg);

  float m_[4], l_[4];
  f32x4 acc[2];
  #pragma unroll
  for (int i = 0; i < 4; i++) { m_[i] = -1e30f; l_[i] = 0.f; }
  #pragma unroll
  for (int dt = 0; dt < 2; dt++)
    #pragma unroll
    for (int i = 0; i < 4; i++) acc[dt][i] = 0.f;

  bf16x8 kreg = *(const bf16x8*)(k + (size_t)(t0 * 64 + sr) * kD + hoff + sk);
  bf16x8 vreg = *(const bf16x8*)(v + (size_t)(t0 * 64 + sr) * kD + hoff + sk);

  for (int t = 0; t < tpb; t++) {
    __syncthreads();
    *(bf16x8*)&sh.at.Kl[sr][sk] = kreg;
    #pragma unroll
    for (int j = 0; j < 8; j++) sh.at.Vt[sk + j][sr] = (unsigned short)vreg[j];
    __syncthreads();
    if (t + 1 < tpb) {
      const size_t nx = (size_t)((t0 + t + 1) * 64 + sr) * kD + hoff + sk;
      kreg = *(const bf16x8*)(k + nx);
      vreg = *(const bf16x8*)(v + nx);
    }
    f32x4 sc[4];
    #pragma unroll
    for (int c = 0; c < 4; c++) {
      f32x4 z;
      #pragma unroll
      for (int i = 0; i < 4; i++) z[i] = 0.f;
      bf16x8 kf = *(bf16x8*)&sh.at.Kl[c * 16 + lr][8 * lg];
      sc[c] = __builtin_amdgcn_mfma_f32_16x16x32_bf16(qf, kf, z, 0, 0, 0);
    }
    float tm[4];
    #pragma unroll
    for (int i = 0; i < 4; i++)
      tm[i] = fmaxf(fmaxf(sc[0][i], sc[1][i]), fmaxf(sc[2][i], sc[3][i]));
    #pragma unroll
    for (int mm = 1; mm <= 8; mm <<= 1)
      #pragma unroll
      for (int i = 0; i < 4; i++) tm[i] = fmaxf(tm[i], __shfl_xor(tm[i], mm));
    float pv[4][4], rs[4], corr[4];
    #pragma unroll
    for (int i = 0; i < 4; i++) {
      const float nm = fmaxf(m_[i], tm[i]);
      corr[i] = __expf(m_[i] - nm);
      m_[i] = nm;
      rs[i] = 0.f;
    }
    #pragma unroll
    for (int c = 0; c < 4; c++)
      #pragma unroll
      for (int i = 0; i < 4; i++) {
        pv[c][i] = __expf(sc[c][i] - m_[i]);
        rs[i] += pv[c][i];
      }
    #pragma unroll
    for (int mm = 1; mm <= 8; mm <<= 1)
      #pragma unroll
      for (int i = 0; i < 4; i++) rs[i] += __shfl_xor(rs[i], mm);
    #pragma unroll
    for (int i = 0; i < 4; i++) {
      l_[i] = l_[i] * corr[i] + rs[i];
      acc[0][i] *= corr[i];
      acc[1][i] *= corr[i];
    }
    #pragma unroll
    for (int c = 0; c < 4; c++)
      #pragma unroll
      for (int i = 0; i < 4; i++)
        sh.at.Pl[w][4 * lg + i][c * 16 + lr] = f2b(pv[c][i]);
    __syncthreads();
    #pragma unroll
    for (int k2 = 0; k2 < 2; k2++) {
      bf16x8 pf_ = *(bf16x8*)&sh.at.Pl[w][lr][k2 * 32 + 8 * lg];
      #pragma unroll
      for (int dt = 0; dt < 2; dt++) {
        bf16x8 vf = *(bf16x8*)&sh.at.Vt[dt * 16 + lr][k2 * 32 + 8 * lg];
        acc[dt] = __builtin_amdgcn_mfma_f32_16x16x32_bf16(pf_, vf, acc[dt], 0, 0, 0);
      }
    }
  }

  const int pb = s * 8 + h;
  float* pa = pacc + (size_t)pb * kSEQ * kHD;
  float* pm = pml + (size_t)pb * kSEQ * 2;
  #pragma unroll
  for (int dt = 0; dt < 2; dt++)
    #pragma unroll
    for (int i = 0; i < 4; i++) {
      const int gr = q0 + w * 16 + 4 * lg + i;
      pa[(size_t)gr * kHD + dt * 16 + lr] = acc[dt][i];
    }
  if (lr == 0) {
    #pragma unroll
    for (int i = 0; i < 4; i++) {
      const int gr = q0 + w * 16 + 4 * lg + i;
      float2 ml; ml.x = m_[i]; ml.y = l_[i];
      *(float2*)&pm[(size_t)gr * 2] = ml;
    }
  }
}

__global__ __launch_bounds__(256) void k_attn(MegaParams p) {
  __shared__ SharedU sh;
  const int job = blockIdx.x;
  const int qb_ = job & 31, h = (job >> 5) & 7, s = job >> 8;
  attn_job(sh, qb_, h, s, p.tpb, p.qb, p.kb, p.vb, p.pacc, p.pml);
}

// ---------------------------------------------------------------- LN over 16 rows, 16-wave block, each wave owns 16 cols
__device__ __forceinline__ void ln16w(float v[4], float2 (*red)[16],
                                      const float* gam, const float* bet,
                                      int ww, int lg, int lr) {
  float ps[4], ps2[4];
  #pragma unroll
  for (int i = 0; i < 4; i++) { ps[i] = v[i]; ps2[i] = v[i] * v[i]; }
  #pragma unroll
  for (int mm = 1; mm <= 8; mm <<= 1)
    #pragma unroll
    for (int i = 0; i < 4; i++) {
      ps[i] += __shfl_xor(ps[i], mm);
      ps2[i] += __shfl_xor(ps2[i], mm);
    }
  if (lr == 0) {
    #pragma unroll
    for (int i = 0; i < 4; i++) {
      float2 t; t.x = ps[i]; t.y = ps2[i];
      red[ww][4 * lg + i] = t;
    }
  }
  __syncthreads();
  #pragma unroll
  for (int i = 0; i < 4; i++) {
    const int ri = 4 * lg + i;
    float sx = 0.f, sx2 = 0.f;
    #pragma unroll
    for (int w2 = 0; w2 < 16; w2++) {
      float2 t = red[w2][ri];
      sx += t.x; sx2 += t.y;
    }
    const float mean = sx * (1.0f / 256.0f);
    const float var = sx2 * (1.0f / 256.0f) - mean * mean;
    const float rstd = rsqrtf(var + 1e-5f);
    const int col = ww * 16 + lr;
    v[i] = (v[i] - mean) * rstd * gam[col] + bet[col];
  }
}

// ---------------------------------------------------------------- staged GEMM slice
// All 1024 threads cooperatively stage [256 N-rows][32 K] chunks of BT into
// a double-buffered LDS tile; wave ww's MFMA reads its 16-col slice from LDS.
// One barrier per chunk; next chunk's global load issues before the MFMA.
__device__ __forceinline__ f32x4 gemm_stage(
    int nchunks, const unsigned short* __restrict__ BT, int ldb, int nbase,
    const unsigned short* __restrict__ Abase, int astr,
    unsigned short (*Bst)[36], int tid, int ww, int lg, int lr) {
  const int sn = tid >> 2, sk = (tid & 3) * 8;
  const unsigned short* Bsrc = BT + (size_t)(nbase + sn) * ldb + sk;
  f32x4 acc = {0.f, 0.f, 0.f, 0.f};
  bf16x8 bv = *(const bf16x8*)Bsrc;
  *(bf16x8*)&Bst[sn][sk] = bv;
  __syncthreads();
  for (int kk = 0; kk < nchunks; kk++) {
    if (kk + 1 < nchunks)
      bv = *(const bf16x8*)(Bsrc + (kk + 1) * 32);
    bf16x8 af = *(const bf16x8*)(Abase + (size_t)lr * astr + kk * 32 + 8 * lg);
    bf16x8 bf = *(const bf16x8*)&Bst[(kk & 1) * 256 + ww * 16 + lr][8 * lg];
    acc = __builtin_amdgcn_mfma_f32_16x16x32_bf16(af, bf, acc, 0, 0, 0);
    if (kk + 1 < nchunks)
      *(bf16x8*)&Bst[((kk + 1) & 1) * 256 + sn][sk] = bv;
    __syncthreads();
  }
  return acc;
}

// ---------------------------------------------------------------- fused layer block (1024 thr / 16 waves):
// combine + Wo + resid + LN1 + FF1 + gelu + FF2 + resid + LN2 (+ next-layer QKV)
template <bool QKV, int NSPLIT>
__global__ __launch_bounds__(1024) void k_block(MegaParams p, int lyr) {
  __shared__ unsigned short As[16][264];
  __shared__ unsigned short Hs[16][1032];
  __shared__ unsigned short Bst[512][36];   // double-buffered B chunk
  __shared__ float2 red[16][16];
  const int tid = threadIdx.x;
  const int ww = tid >> 6, l = tid & 63, lg = l >> 4, lr = l & 15;
  const int r0 = blockIdx.x * 16;

  // ---- phase A: softmax-combine attn partials -> As (fully unrolled loads)
  {
    const int row = r0 + (tid >> 6);
    const int kc = (tid & 63) * 4;
    const int h_ = kc >> 5;
    const int d0 = kc & 31;
    float pmx[NSPLIT], pll[NSPLIT];
    #pragma unroll
    for (int s2 = 0; s2 < NSPLIT; s2++) {
      const float2 t =
          *(const float2*)&p.pml[((size_t)(s2 * 8 + h_) * kSEQ + row) * 2];
      pmx[s2] = t.x; pll[s2] = t.y;
    }
    f32x4 pa_[NSPLIT];
    #pragma unroll
    for (int s2 = 0; s2 < NSPLIT; s2++)
      pa_[s2] = *(const f32x4*)(p.pacc +
                                ((size_t)(s2 * 8 + h_) * kSEQ + row) * kHD + d0);
    float mx = -1e30f;
    #pragma unroll
    for (int s2 = 0; s2 < NSPLIT; s2++) mx = fmaxf(mx, pmx[s2]);
    float L = 0.f;
    float o[4] = {0.f, 0.f, 0.f, 0.f};
    #pragma unroll
    for (int s2 = 0; s2 < NSPLIT; s2++) {
      const float es = __expf(pmx[s2] - mx);
      L += pll[s2] * es;
      #pragma unroll
      for (int j = 0; j < 4; j++) o[j] += pa_[s2][j] * es;
    }
    const float inv = 1.0f / L;
    unsigned short* dst = &As[tid >> 6][kc];
    #pragma unroll
    for (int j = 0; j < 4; j++) dst[j] = f2b(o[j] * inv);
  }
  __syncthreads();

  // ---- phase B: Wo GEMM (staged) + bias + resid + LN1
  float yv[4];
  {
    f32x4 acc = gemm_stage(8, p.wT + p.oWoT[lyr], 256, 0, &As[0][0], 264,
                           Bst, tid, ww, lg, lr);
    const float* bias = p.bo + lyr * kD;
    const int col = ww * 16 + lr;
    #pragma unroll
    for (int i = 0; i < 4; i++) {
      const int gr = r0 + 4 * lg + i;
      yv[i] = acc[i] + bias[col] + p.xf[(size_t)gr * kD + col];
    }
    ln16w(yv, red, p.ln1g + lyr * kD, p.ln1b + lyr * kD, ww, lg, lr);
    __syncthreads();   // all As (ctx) reads done before overwrite
    #pragma unroll
    for (int i = 0; i < 4; i++)
      As[4 * lg + i][col] = f2b(yv[i]);
  }
  __syncthreads();

  // ---- phase C: FF1 + fast-gelu -> Hs (4 col-groups of 256)
  {
    const unsigned short* BT = p.wT + p.oFF1[lyr];
    const float* bias = p.bff1 + lyr * kFF;
    for (int ng = 0; ng < 4; ng++) {
      f32x4 acc = gemm_stage(8, BT, 256, ng * 256, &As[0][0], 264,
                             Bst, tid, ww, lg, lr);
      const int col = ng * 256 + ww * 16 + lr;
      #pragma unroll
      for (int i = 0; i < 4; i++) {
        const float v = acc[i] + bias[col];
        const float u = 0.7978845608028654f * (v + 0.044715f * v * v * v);
        const float g = v / (1.0f + __expf(-2.0f * u));  // v*sigmoid(2u)
        Hs[4 * lg + i][col] = f2b(g);
      }
    }
  }
  __syncthreads();

  // ---- phase D: FF2 (staged, K=1024) + bias + resid(y) + LN2
  float zv[4];
  {
    f32x4 acc = gemm_stage(32, p.wT + p.oFF2[lyr], 1024, 0, &Hs[0][0], 1032,
                           Bst, tid, ww, lg, lr);
    const float* bias = p.bff2 + lyr * kD;
    const int col = ww * 16 + lr;
    #pragma unroll
    for (int i = 0; i < 4; i++) zv[i] = acc[i] + bias[col] + yv[i];
    ln16w(zv, red, p.ln2g + lyr * kD, p.ln2b + lyr * kD, ww, lg, lr);
    #pragma unroll
    for (int i = 0; i < 4; i++) {
      const int gr = r0 + 4 * lg + i;
      p.xf[(size_t)gr * kD + col] = zv[i];
      p.xb[(size_t)gr * kD + col] = f2b(zv[i]);
      if constexpr (QKV) As[4 * lg + i][col] = f2b(zv[i]);
    }
  }

  // ---- phase E: next-layer QKV projection from z (3 col-groups = q,k,v)
  if constexpr (QKV) {
    __syncthreads();
    const unsigned short* BT = p.wT + p.oQKV[lyr + 1];
    for (int ng = 0; ng < 3; ng++) {
      f32x4 acc = gemm_stage(8, BT, 256, ng * 256, &As[0][0], 264,
                             Bst, tid, ww, lg, lr);
      const int cc = ww * 16 + lr;
      const float* bp = (ng == 0) ? (p.bq + (lyr + 1) * 256)
                        : (ng == 1 ? (p.bk + (lyr + 1) * 256)
                                   : (p.bv + (lyr + 1) * 256));
      unsigned short* op = (ng == 0) ? p.qb : (ng == 1 ? p.kb : p.vb);
      #pragma unroll
      for (int i = 0; i < 4; i++) {
        const int gr = r0 + 4 * lg + i;
        float v = acc[i] + bp[cc];
        if (ng == 0) v *= 0.17677669529663687f;
        op[(size_t)gr * kD + cc] = f2b(v);
      }
    }
  }
}

// ---------------------------------------------------------------- heads
__global__ __launch_bounds__(256) void k_h1(MegaParams p) {
  __shared__ float tl[256];
  __shared__ float red[4][64];
  const int tid = threadIdx.x;
  tl[tid] = p.xf[tid];
  __syncthreads();
  const int jj = blockIdx.x * 64;
  const bool actor = jj < 512;
  const float* W = actor ? p.aW1 : p.cW1;
  const float* b = actor ? p.ab1 : p.cb1;
  const int j0 = actor ? jj : jj - 512;
  const int ks = tid >> 6, j = tid & 63;
  float s = 0.f;
  #pragma unroll 4
  for (int k2 = ks * 64; k2 < ks * 64 + 64; k2++)
    s += tl[k2] * W[(size_t)k2 * 512 + j0 + j];
  red[ks][j] = s;
  __syncthreads();
  if (tid < 64) {
    float t = red[0][tid] + red[1][tid] + red[2][tid] + red[3][tid] + b[j0 + tid];
    p.h1[jj + tid] = tanhf(t);
  }
}

__global__ __launch_bounds__(256) void k_h2(MegaParams p) {
  __shared__ float tl[512];
  __shared__ float red[4][64];
  const int tid = threadIdx.x;
  const int jj = blockIdx.x * 64;
  const bool actor = jj < 512;
  const float* hin = actor ? p.h1 : p.h1 + 512;
  tl[tid] = hin[tid];
  tl[tid + 256] = hin[tid + 256];
  __syncthreads();
  const float* W = actor ? p.aW2 : p.cW2;
  const float* b = actor ? p.ab2 : p.cb2;
  const int j0 = actor ? jj : jj - 512;
  const int ks = tid >> 6, j = tid & 63;
  float s = 0.f;
  #pragma unroll 4
  for (int k2 = ks * 128; k2 < ks * 128 + 128; k2++)
    s += tl[k2] * W[(size_t)k2 * 512 + j0 + j];
  red[ks][j] = s;
  __syncthreads();
  if (tid < 64) {
    float t = red[0][tid] + red[1][tid] + red[2][tid] + red[3][tid] + b[j0 + tid];
    p.h2[jj + tid] = tanhf(t);
  }
}

__global__ __launch_bounds__(256) void k_h3(MegaParams p) {
  __shared__ float ha[512], hc[512], vred[4];
  const int tid = threadIdx.x;
  ha[tid] = p.h2[tid];
  ha[tid + 256] = p.h2[tid + 256];
  hc[tid] = p.h2[512 + tid];
  hc[tid + 256] = p.h2[768 + tid];
  __syncthreads();
  const int g = tid >> 4, l16 = tid & 15;
  float s = 0.f;
  for (int k2 = l16 * 32; k2 < l16 * 32 + 32; k2++)
    s += ha[k2] * p.aWo[(size_t)k2 * kA + g];
  #pragma unroll
  for (int mm = 1; mm <= 8; mm <<= 1) s += __shfl_xor(s, mm);
  if (l16 == 0) p.out[1 + g] = s + p.abo[g];
  float vv = hc[tid] * p.cWo[tid] + hc[tid + 256] * p.cWo[tid + 256];
  #pragma unroll
  for (int mm = 1; mm <= 32; mm <<= 1) vv += __shfl_xor(vv, mm);
  if ((tid & 63) == 0) vred[tid >> 6] = vv;
  __syncthreads();
  if (tid == 0)
    p.out[0] = vred[0] + vred[1] + vred[2] + vred[3] + p.cbo[0];
  p.out[17 + tid] = tanhf(p.obs[tid]);
}

// ---------------------------------------------------------------- launch
extern "C" void kernel_launch(void* const* d_in, const int* in_sizes, int n_in,
                              void* d_out, int out_size, void* d_ws, size_t ws_size,
                              hipStream_t stream) {
  const float* obs   = (const float*)d_in[0];
  const float* oldv  = (const float*)d_in[1];
  const float* Wcore = (const float*)d_in[2];
  const float* bcore = (const float*)d_in[3];
  const float* Wmemo = (const float*)d_in[4];
  const float* bmemo = (const float*)d_in[5];
  const float* Wq    = (const float*)d_in[6];
  const float* bq    = (const float*)d_in[7];
  const float* Wk    = (const float*)d_in[8];
  const float* bk    = (const float*)d_in[9];
  const float* Wv    = (const float*)d_in[10];
  const float* bv    = (const float*)d_in[11];
  const float* Wo    = (const float*)d_in[12];
  const float* bo    = (const float*)d_in[13];
  const float* ln1g  = (const float*)d_in[14];
  const float* ln1b  = (const float*)d_in[15];
  const float* ln2g  = (const float*)d_in[16];
  const float* ln2b  = (const float*)d_in[17];
  const float* Wff1  = (const float*)d_in[18];
  const float* bff1  = (const float*)d_in[19];
  const float* Wff2  = (const float*)d_in[20];
  const float* bff2  = (const float*)d_in[21];

  MegaParams P;
  P.obs = obs; P.oldv = oldv; P.Wcore = Wcore; P.bcore = bcore;
  P.Wmemo0 = Wmemo; P.bmemo = bmemo; P.Wmemo2 = Wmemo + 256 * 256;
  P.bq = bq; P.bk = bk; P.bv = bv; P.bo = bo;
  P.ln1g = ln1g; P.ln1b = ln1b; P.ln2g = ln2g; P.ln2b = ln2b;
  P.bff1 = bff1; P.bff2 = bff2;
  P.aW1 = (const float*)d_in[22]; P.ab1 = (const float*)d_in[23];
  P.aW2 = (const float*)d_in[24]; P.ab2 = (const float*)d_in[25];
  P.aWo = (const float*)d_in[26]; P.abo = (const float*)d_in[27];
  P.cW1 = (const float*)d_in[28]; P.cb1 = (const float*)d_in[29];
  P.cW2 = (const float*)d_in[30]; P.cb2 = (const float*)d_in[31];
  P.cWo = (const float*)d_in[32]; P.cbo = (const float*)d_in[33];

  char* ws = (char*)d_ws;
  P.xf = (float*)(ws + 0);                           // 2 MB
  P.xb = (unsigned short*)(ws + (2u << 20));         // 1 MB
  P.qb = (unsigned short*)(ws + (3u << 20));         // 1 MB
  P.kb = (unsigned short*)(ws + (4u << 20));         // 1 MB
  P.vb = (unsigned short*)(ws + (5u << 20));         // 1 MB
  P.wT = (unsigned short*)(ws + (6u << 20));         // ~3 MB
  P.h1 = (float*)(ws + (10u << 20));
  P.h2 = (float*)(ws + (10u << 20) + 8192);
  P.out = (float*)d_out;

  int nsplit = 8;
  const size_t paccOff = (size_t)14u << 20;
  const size_t pmlOff  = (size_t)31u << 20;
  while (nsplit > 1 &&
         (paccOff + (size_t)nsplit * 8 * kSEQ * kHD * 4 > pmlOff ||
          pmlOff + (size_t)nsplit * 8 * kSEQ * 2 * 4 > ws_size))
    nsplit >>= 1;
  P.pacc = (float*)(ws + paccOff);
  P.pml  = (float*)(ws + pmlOff);
  P.nsplit = nsplit;
  P.tpb = 32 / nsplit;

  int cur = 0;
  for (int l2 = 0; l2 < 2; l2++) {
    P.oQKV[l2] = cur; cur += 196608;
    P.oWoT[l2] = cur; cur += 65536;
    P.oFF1[l2] = cur; cur += 262144;
    P.oFF2[l2] = cur; cur += 262144;
  }

  int idx = 0, ts = 0;
  auto add = [&](const float* s, int K, int N, int dst) {
    P.tab.src[idx] = s; P.tab.K[idx] = K; P.tab.N[idx] = N;
    P.tab.dst[idx] = dst; P.tab.tstart[idx] = ts;
    ts += (K >> 6) * (N >> 6); idx++;
  };
  for (int l2 = 0; l2 < 2; l2++) {
    add(Wq + l2 * 65536, 256, 256, P.oQKV[l2]);
    add(Wk + l2 * 65536, 256, 256, P.oQKV[l2] + 65536);
    add(Wv + l2 * 65536, 256, 256, P.oQKV[l2] + 131072);
    add(Wo + l2 * 65536, 256, 256, P.oWoT[l2]);
    add(Wff1 + l2 * 262144, 256, 1024, P.oFF1[l2]);
    add(Wff2 + l2 * 262144, 1024, 256, P.oFF2[l2]);
  }
  P.tab.tstart[idx] = ts;
  P.convJobs = ts;

  auto launch_block = [&](bool qkv, int lyr) {
    if (qkv) {
      switch (nsplit) {
        case 8: k_block<true, 8><<<128, 1024, 0, stream>>>(P, lyr); break;
        case 4: k_block<true, 4><<<128, 1024, 0, stream>>>(P, lyr); break;
        case 2: k_block<true, 2><<<128, 1024, 0, stream>>>(P, lyr); break;
        default: k_block<true, 1><<<128, 1024, 0, stream>>>(P, lyr); break;
      }
    } else {
      switch (nsplit) {
        case 8: k_block<false, 8><<<128, 1024, 0, stream>>>(P, lyr); break;
        case 4: k_block<false, 4><<<128, 1024, 0, stream>>>(P, lyr); break;
        case 2: k_block<false, 2><<<128, 1024, 0, stream>>>(P, lyr); break;
        default: k_block<false, 1><<<128, 1024, 0, stream>>>(P, lyr); break;
      }
    }
  };

  k_cvm<<<256 + ts + 1, 256, 0, stream>>>(P);
  k_qkv<<<768, 256, 0, stream>>>(P, 0);
  k_attn<<<256 * nsplit, 256, 0, stream>>>(P);
  launch_block(true, 0);
  k_attn<<<256 * nsplit, 256, 0, stream>>>(P);
  launch_block(false, 1);
  k_h1<<<16, 256, 0, stream>>>(P);
  k_h2<<<16, 256, 0, stream>>>(P);
  k_h3<<<1, 256, 0, stream>>>(P);
}

// Round 12
// 190.292 us; speedup vs baseline: 1.5554x; 1.5554x over previous
//
#include <hip/hip_runtime.h>
#include <stdint.h>

typedef __attribute__((ext_vector_type(8))) short bf16x8;
typedef __attribute__((ext_vector_type(4))) float f32x4;

constexpr int kSEQ = 2048;   // 1 + 2047
constexpr int kD   = 256;
constexpr int kHD  = 32;
constexpr int kFF  = 1024;
constexpr int kA   = 16;

__device__ __forceinline__ unsigned short f2b(float f) {
  union { float f; unsigned int u; } v; v.f = f;
  unsigned int r = v.u + 0x7FFFu + ((v.u >> 16) & 1u);
  return (unsigned short)(r >> 16);
}

struct ConvTable {
  const float* src[13];
  int K[13];
  int N[13];
  int dst[13];
  int tstart[14];
};

union SharedU {
  struct { unsigned short lt[64][72]; } cv;
  struct { unsigned short Al[64][40]; unsigned short Bl[32][40]; } g64;
  struct { unsigned short Kl[64][40]; unsigned short Vt[32][72];
           unsigned short Pl[4][16][72]; } at;
  struct { unsigned short As[16][264]; float2 red[4][16]; } lg;
};

struct MegaParams {
  ConvTable tab;
  const float *obs, *oldv, *Wcore, *bcore, *Wmemo0, *bmemo, *Wmemo2;
  const float *bq, *bk, *bv, *bo, *ln1g, *ln1b, *ln2g, *ln2b, *bff1, *bff2;
  const float *aW1, *ab1, *aW2, *ab2, *aWo, *abo;
  const float *cW1, *cb1, *cW2, *cb2, *cWo, *cbo;
  float* xf; unsigned short* xb;
  unsigned short *qb, *kb, *vb, *hb, *wT;
  float *pacc, *pml, *pf, *h1, *h2, *out;
  int oQKV[2], oWoT[2], oFF1[2], oFF2[2];
  int convJobs, nsplit, tpb;
};

// ---------------------------------------------------------------- conv job
__device__ void conv_job(const MegaParams& p, SharedU& sh, int job) {
  const int tid = threadIdx.x;
  if (job == p.convJobs) {  // row-0 embed
    float a = p.bcore[tid];
    #pragma unroll 8
    for (int k = 0; k < 256; k++) a += p.obs[k] * p.Wcore[k * kD + tid];
    p.xf[tid] = a;
    p.xb[tid] = f2b(a);
    return;
  }
  int m = 0;
  while (job >= p.tab.tstart[m + 1]) m++;
  const int tloc = job - p.tab.tstart[m];
  const int N = p.tab.N[m], K = p.tab.K[m];
  const int ntile = N >> 6;
  const int k0 = (tloc / ntile) * 64, n0 = (tloc % ntile) * 64;
  const float* src = p.tab.src[m];
  {
    const int r = tid >> 2, c16 = (tid & 3) * 16;
    const float* sp = src + (size_t)(k0 + r) * N + n0 + c16;
    #pragma unroll
    for (int j = 0; j < 16; j++) sh.cv.lt[r][c16 + j] = f2b(sp[j]);
  }
  __syncthreads();
  {
    const int n = tid >> 2, kc = (tid & 3) * 16;
    unsigned short* dp = p.wT + p.tab.dst[m] + (size_t)(n0 + n) * K + k0 + kc;
    unsigned short g[16];
    #pragma unroll
    for (int j = 0; j < 16; j++) g[j] = sh.cv.lt[kc + j][n];
    *(bf16x8*)dp = *(bf16x8*)&g[0];
    *(bf16x8*)(dp + 8) = *(bf16x8*)&g[8];
  }
}

// ---------------------------------------------------------------- memo job
__device__ void memo_job(const MegaParams& p, SharedU& sh, int job) {
  const int tid = threadIdx.x;
  const int w = tid >> 6, l = tid & 63, lg = l >> 4, lr = l & 15;
  const int sr = tid >> 2, sk = (tid & 3) * 8;
  const int kr = tid >> 3, nc = (tid & 7) * 4;
  const int m0 = (job & 31) * 64, n0 = (job >> 5) * 32;
  f32x4 acc[2];
  #pragma unroll
  for (int c = 0; c < 2; c++)
    #pragma unroll
    for (int i = 0; i < 4; i++) acc[c][i] = 0.f;

  auto loadA = [&](int k0) -> bf16x8 {
    bf16x8 av;
    if (m0 + sr < 2047) {
      const float* ap = p.oldv + (size_t)(m0 + sr) * 256 + k0 + sk;
      #pragma unroll
      for (int j = 0; j < 8; j++) av[j] = (short)f2b(ap[j]);
    } else {
      #pragma unroll
      for (int j = 0; j < 8; j++) av[j] = 0;
    }
    return av;
  };
  auto loadB = [&](int k0, float* b4) {
    const float* bp = p.Wmemo0 + (size_t)(k0 + kr) * kD + n0 + nc;
    #pragma unroll
    for (int j = 0; j < 4; j++) b4[j] = bp[j];
  };

  bf16x8 av = loadA(0);
  float b4[4];
  loadB(0, b4);

  for (int k0 = 0; k0 < 256; k0 += 32) {
    __syncthreads();
    *(bf16x8*)&sh.g64.Al[sr][sk] = av;
    #pragma unroll
    for (int j = 0; j < 4; j++) sh.g64.Bl[nc + j][kr] = f2b(b4[j]);
    __syncthreads();
    if (k0 + 32 < 256) {
      av = loadA(k0 + 32);
      loadB(k0 + 32, b4);
    }
    bf16x8 af = *(bf16x8*)&sh.g64.Al[w * 16 + lr][8 * lg];
    #pragma unroll
    for (int c = 0; c < 2; c++) {
      bf16x8 bf = *(bf16x8*)&sh.g64.Bl[c * 16 + lr][8 * lg];
      acc[c] = __builtin_amdgcn_mfma_f32_16x16x32_bf16(af, bf, acc[c], 0, 0, 0);
    }
  }

  #pragma unroll
  for (int c = 0; c < 2; c++)
    #pragma unroll
    for (int i = 0; i < 4; i++) {
      const int gr = m0 + w * 16 + 4 * lg + i;
      const int gc = n0 + c * 16 + lr;
      if (gr >= 2047) continue;
      const float v = acc[c][i] + p.bmemo[gc] + p.Wmemo2[(size_t)gr * kD + gc];
      p.xf[(size_t)(gr + 1) * kD + gc] = v;
      p.xb[(size_t)(gr + 1) * kD + gc] = f2b(v);
    }
}

__global__ __launch_bounds__(256) void k_cvm(MegaParams p) {
  __shared__ SharedU sh;
  if (blockIdx.x < 256) memo_job(p, sh, blockIdx.x);
  else conv_job(p, sh, blockIdx.x - 256);
}

// ---------------------------------------------------------------- 64x32 GEMM job
// EPI 1: qkv (+bias, q-scale, split)  EPI 2: ff1 fast-gelu  EPI 3: fp32 partial
template <int EPI>
__device__ __forceinline__ void gemm_job(
    SharedU& sh, int m0, int n0, const unsigned short* Ap, int lda, int Kloop,
    const unsigned short* BT, int ldb,
    const float* p0, const float* p1, const float* p2,
    void* o0, void* o1, void* o2) {
  const int tid = threadIdx.x;
  const int w = tid >> 6, l = tid & 63, lg = l >> 4, lr = l & 15;
  const int sr = tid >> 2, sk = (tid & 3) * 8;
  f32x4 acc[2];
  #pragma unroll
  for (int c = 0; c < 2; c++)
    #pragma unroll
    for (int i = 0; i < 4; i++) acc[c][i] = 0.f;

  bf16x8 av = *(const bf16x8*)(Ap + (size_t)(m0 + sr) * lda + sk);
  bf16x8 bv;
  if (tid < 128) bv = *(const bf16x8*)(BT + (size_t)(n0 + sr) * ldb + sk);

  for (int k0 = 0; k0 < Kloop; k0 += 32) {
    __syncthreads();
    *(bf16x8*)&sh.g64.Al[sr][sk] = av;
    if (tid < 128) *(bf16x8*)&sh.g64.Bl[sr][sk] = bv;
    __syncthreads();
    if (k0 + 32 < Kloop) {
      av = *(const bf16x8*)(Ap + (size_t)(m0 + sr) * lda + k0 + 32 + sk);
      if (tid < 128)
        bv = *(const bf16x8*)(BT + (size_t)(n0 + sr) * ldb + k0 + 32 + sk);
    }
    bf16x8 af = *(bf16x8*)&sh.g64.Al[w * 16 + lr][8 * lg];
    #pragma unroll
    for (int c = 0; c < 2; c++) {
      bf16x8 bf = *(bf16x8*)&sh.g64.Bl[c * 16 + lr][8 * lg];
      acc[c] = __builtin_amdgcn_mfma_f32_16x16x32_bf16(af, bf, acc[c], 0, 0, 0);
    }
  }

  #pragma unroll
  for (int c = 0; c < 2; c++) {
    #pragma unroll
    for (int i = 0; i < 4; i++) {
      const int gr = m0 + w * 16 + 4 * lg + i;
      const int gc = n0 + c * 16 + lr;
      float v = acc[c][i];
      if constexpr (EPI == 1) {
        const int t = gc >> 8, cc = gc & 255;
        const float* bp = (t == 0) ? p0 : (t == 1 ? p1 : p2);
        unsigned short* op = (t == 0) ? (unsigned short*)o0
                              : (t == 1 ? (unsigned short*)o1
                                        : (unsigned short*)o2);
        v += bp[cc];
        if (t == 0) v *= 0.17677669529663687f;  // 1/sqrt(32) folded into q
        op[(size_t)gr * kD + cc] = f2b(v);
      } else if constexpr (EPI == 2) {
        v += p0[gc];
        const float u = 0.7978845608028654f * (v + 0.044715f * v * v * v);
        const float g = v / (1.0f + __expf(-2.0f * u));  // v*sigmoid(2u)
        ((unsigned short*)o0)[(size_t)gr * kFF + gc] = f2b(g);
      } else {
        ((float*)o0)[(size_t)gr * kD + gc] = v;
      }
    }
  }
}

__global__ __launch_bounds__(256) void k_qkv(MegaParams p, int lyr) {
  __shared__ SharedU sh;
  const int job = blockIdx.x;
  const int m0 = (job & 31) * 64, n0 = (job >> 5) * 32;
  gemm_job<1>(sh, m0, n0, p.xb, 256, 256, p.wT + p.oQKV[lyr], 256,
              p.bq + lyr * 256, p.bk + lyr * 256, p.bv + lyr * 256,
              p.qb, p.kb, p.vb);
}

__global__ __launch_bounds__(256) void k_ff1(MegaParams p, int lyr) {
  __shared__ SharedU sh;
  const int job = blockIdx.x;
  const int m0 = (job & 31) * 64, n0 = (job >> 5) * 32;
  gemm_job<2>(sh, m0, n0, p.xb, 256, 256, p.wT + p.oFF1[lyr], 256,
              p.bff1 + lyr * 1024, nullptr, nullptr, p.hb, nullptr, nullptr);
}

__global__ __launch_bounds__(256) void k_ff2p(MegaParams p, int lyr) {
  __shared__ SharedU sh;
  const int job = blockIdx.x;
  const int m0 = (job & 31) * 64;
  const int n0 = ((job >> 5) & 7) * 32;
  const int kc = (job >> 8) * 256;
  gemm_job<3>(sh, m0, n0, p.hb + kc, kFF, 256,
              p.wT + p.oFF2[lyr] + kc, kFF, nullptr, nullptr, nullptr,
              p.pf + (size_t)(job >> 8) * kSEQ * kD, nullptr, nullptr);
}

// ---------------------------------------------------------------- attention
__device__ void attn_job(SharedU& sh, int qb_, int h, int s, int tpb,
                         const unsigned short* q, const unsigned short* k,
                         const unsigned short* v, float* pacc, float* pml) {
  const int tid = threadIdx.x;
  const int w = tid >> 6, l = tid & 63, lg = l >> 4, lr = l & 15;
  const int q0 = qb_ * 64;
  const int hoff = h * kHD;
  const int sr = tid >> 2, sk = (tid & 3) * 8;
  const int t0 = s * tpb;

  const bf16x8 qf =
      *(const bf16x8*)(q + (size_t)(q0 + w * 16 + lr) * kD + hoff + 8 * lg);

  float m_[4], l_[4];
  f32x4 acc[2];
  #pragma unroll
  for (int i = 0; i < 4; i++) { m_[i] = -1e30f; l_[i] = 0.f; }
  #pragma unroll
  for (int dt = 0; dt < 2; dt++)
    #pragma unroll
    for (int i = 0; i < 4; i++) acc[dt][i] = 0.f;

  bf16x8 kreg = *(const bf16x8*)(k + (size_t)(t0 * 64 + sr) * kD + hoff + sk);
  bf16x8 vreg = *(const bf16x8*)(v + (size_t)(t0 * 64 + sr) * kD + hoff + sk);

  for (int t = 0; t < tpb; t++) {
    __syncthreads();
    *(bf16x8*)&sh.at.Kl[sr][sk] = kreg;
    #pragma unroll
    for (int j = 0; j < 8; j++) sh.at.Vt[sk + j][sr] = (unsigned short)vreg[j];
    __syncthreads();
    if (t + 1 < tpb) {
      const size_t nx = (size_t)((t0 + t + 1) * 64 + sr) * kD + hoff + sk;
      kreg = *(const bf16x8*)(k + nx);
      vreg = *(const bf16x8*)(v + nx);
    }
    f32x4 sc[4];
    #pragma unroll
    for (int c = 0; c < 4; c++) {
      f32x4 z;
      #pragma unroll
      for (int i = 0; i < 4; i++) z[i] = 0.f;
      bf16x8 kf = *(bf16x8*)&sh.at.Kl[c * 16 + lr][8 * lg];
      sc[c] = __builtin_amdgcn_mfma_f32_16x16x32_bf16(qf, kf, z, 0, 0, 0);
    }
    float tm[4];
    #pragma unroll
    for (int i = 0; i < 4; i++)
      tm[i] = fmaxf(fmaxf(sc[0][i], sc[1][i]), fmaxf(sc[2][i], sc[3][i]));
    #pragma unroll
    for (int mm = 1; mm <= 8; mm <<= 1)
      #pragma unroll
      for (int i = 0; i < 4; i++) tm[i] = fmaxf(tm[i], __shfl_xor(tm[i], mm));
    float pv[4][4], rs[4], corr[4];
    #pragma unroll
    for (int i = 0; i < 4; i++) {
      const float nm = fmaxf(m_[i], tm[i]);
      corr[i] = __expf(m_[i] - nm);
      m_[i] = nm;
      rs[i] = 0.f;
    }
    #pragma unroll
    for (int c = 0; c < 4; c++)
      #pragma unroll
      for (int i = 0; i < 4; i++) {
        pv[c][i] = __expf(sc[c][i] - m_[i]);
        rs[i] += pv[c][i];
      }
    #pragma unroll
    for (int mm = 1; mm <= 8; mm <<= 1)
      #pragma unroll
      for (int i = 0; i < 4; i++) rs[i] += __shfl_xor(rs[i], mm);
    #pragma unroll
    for (int i = 0; i < 4; i++) {
      l_[i] = l_[i] * corr[i] + rs[i];
      acc[0][i] *= corr[i];
      acc[1][i] *= corr[i];
    }
    #pragma unroll
    for (int c = 0; c < 4; c++)
      #pragma unroll
      for (int i = 0; i < 4; i++)
        sh.at.Pl[w][4 * lg + i][c * 16 + lr] = f2b(pv[c][i]);
    __syncthreads();
    #pragma unroll
    for (int k2 = 0; k2 < 2; k2++) {
      bf16x8 pf_ = *(bf16x8*)&sh.at.Pl[w][lr][k2 * 32 + 8 * lg];
      #pragma unroll
      for (int dt = 0; dt < 2; dt++) {
        bf16x8 vf = *(bf16x8*)&sh.at.Vt[dt * 16 + lr][k2 * 32 + 8 * lg];
        acc[dt] = __builtin_amdgcn_mfma_f32_16x16x32_bf16(pf_, vf, acc[dt], 0, 0, 0);
      }
    }
  }

  const int pb = s * 8 + h;
  float* pa = pacc + (size_t)pb * kSEQ * kHD;
  float* pm = pml + (size_t)pb * kSEQ * 2;
  #pragma unroll
  for (int dt = 0; dt < 2; dt++)
    #pragma unroll
    for (int i = 0; i < 4; i++) {
      const int gr = q0 + w * 16 + 4 * lg + i;
      pa[(size_t)gr * kHD + dt * 16 + lr] = acc[dt][i];
    }
  if (lr == 0) {
    #pragma unroll
    for (int i = 0; i < 4; i++) {
      const int gr = q0 + w * 16 + 4 * lg + i;
      float2 ml; ml.x = m_[i]; ml.y = l_[i];
      *(float2*)&pm[(size_t)gr * 2] = ml;
    }
  }
}

__global__ __launch_bounds__(256) void k_attn(MegaParams p) {
  __shared__ SharedU sh;
  const int job = blockIdx.x;
  const int qb_ = job & 31, h = (job >> 5) & 7, s = job >> 8;
  attn_job(sh, qb_, h, s, p.tpb, p.qb, p.kb, p.vb, p.pacc, p.pml);
}

// ---------------------------------------------------------------- LN epilogue (16 rows x 256 cols)
__device__ __forceinline__ void ln_write(SharedU& sh, float vloc[4][4], int r0,
                                         const float* gam, const float* bet,
                                         float* xf, unsigned short* xb) {
  const int tid = threadIdx.x;
  const int w = tid >> 6, l = tid & 63, lg = l >> 4, lr = l & 15;
  float ps[4], ps2[4];
  #pragma unroll
  for (int i = 0; i < 4; i++) {
    ps[i] = 0.f; ps2[i] = 0.f;
    #pragma unroll
    for (int c = 0; c < 4; c++) {
      ps[i] += vloc[c][i];
      ps2[i] += vloc[c][i] * vloc[c][i];
    }
  }
  #pragma unroll
  for (int mm = 1; mm <= 8; mm <<= 1)
    #pragma unroll
    for (int i = 0; i < 4; i++) {
      ps[i] += __shfl_xor(ps[i], mm);
      ps2[i] += __shfl_xor(ps2[i], mm);
    }
  if (lr == 0) {
    #pragma unroll
    for (int i = 0; i < 4; i++) {
      float2 t; t.x = ps[i]; t.y = ps2[i];
      sh.lg.red[w][4 * lg + i] = t;
    }
  }
  __syncthreads();
  #pragma unroll
  for (int i = 0; i < 4; i++) {
    const int ri = 4 * lg + i;
    float sx = 0.f, sx2 = 0.f;
    #pragma unroll
    for (int ww = 0; ww < 4; ww++) {
      float2 t = sh.lg.red[ww][ri];
      sx += t.x; sx2 += t.y;
    }
    const float mean = sx * (1.0f / 256.0f);
    const float var = sx2 * (1.0f / 256.0f) - mean * mean;
    const float rstd = rsqrtf(var + 1e-5f);
    const int gr = r0 + ri;
    #pragma unroll
    for (int c = 0; c < 4; c++) {
      const int col = w * 64 + c * 16 + lr;
      const float y = (vloc[c][i] - mean) * rstd * gam[col] + bet[col];
      xf[(size_t)gr * kD + col] = y;
      xb[(size_t)gr * kD + col] = f2b(y);
    }
  }
}

// ---------------------------------------------------------------- combine + Wo + resid + LN1
__global__ __launch_bounds__(256) void k_woln(MegaParams p, int lyr) {
  __shared__ SharedU sh;
  const unsigned short* BT = p.wT + p.oWoT[lyr];
  const float* bias = p.bo + lyr * kD;
  const float* gam = p.ln1g + lyr * kD;
  const float* bet = p.ln1b + lyr * kD;
  const int tid = threadIdx.x;
  const int w = tid >> 6, l = tid & 63, lg = l >> 4, lr = l & 15;
  const int r0 = blockIdx.x * 16;
  {  // stage A = softmax-combined ctx rows
    const int row = r0 + (tid >> 4);
    const int kc = (tid & 15) * 16;
    const int h_ = kc >> 5;
    float mx = -1e30f;
    for (int s2 = 0; s2 < p.nsplit; s2++)
      mx = fmaxf(mx, p.pml[((size_t)(s2 * 8 + h_) * kSEQ + row) * 2]);
    float L = 0.f;
    const int d0 = kc & 31;
    float o[16];
    #pragma unroll
    for (int j = 0; j < 16; j++) o[j] = 0.f;
    for (int s2 = 0; s2 < p.nsplit; s2++) {
      const size_t pb = (size_t)(s2 * 8 + h_) * kSEQ + row;
      const float2 t = *(const float2*)&p.pml[pb * 2];
      const float es = __expf(t.x - mx);
      L += t.y * es;
      const float* pa = p.pacc + pb * kHD + d0;
      #pragma unroll
      for (int j = 0; j < 16; j++) o[j] += pa[j] * es;
    }
    const float inv = 1.0f / L;
    unsigned short* dst = &sh.lg.As[tid >> 4][kc];
    #pragma unroll
    for (int j = 0; j < 16; j++) dst[j] = f2b(o[j] * inv);
  }
  __syncthreads();
  f32x4 acc[4];
  #pragma unroll
  for (int c = 0; c < 4; c++)
    #pragma unroll
    for (int i = 0; i < 4; i++) acc[c][i] = 0.f;
  #pragma unroll 2
  for (int k0 = 0; k0 < 256; k0 += 32) {
    bf16x8 af = *(bf16x8*)&sh.lg.As[lr][k0 + 8 * lg];
    #pragma unroll
    for (int c = 0; c < 4; c++) {
      bf16x8 bf = *(const bf16x8*)(BT + (size_t)(w * 64 + c * 16 + lr) * 256 +
                                   k0 + 8 * lg);
      acc[c] = __builtin_amdgcn_mfma_f32_16x16x32_bf16(af, bf, acc[c], 0, 0, 0);
    }
  }
  float vloc[4][4];
  #pragma unroll
  for (int c = 0; c < 4; c++)
    #pragma unroll
    for (int i = 0; i < 4; i++) {
      const int col = w * 64 + c * 16 + lr;
      const int gr = r0 + 4 * lg + i;
      vloc[c][i] = acc[c][i] + bias[col] + p.xf[(size_t)gr * kD + col];
    }
  ln_write(sh, vloc, r0, gam, bet, p.xf, p.xb);
}

// ---------------------------------------------------------------- FF2 reduce + bias + resid + LN2
__global__ __launch_bounds__(256) void k_ln2r(MegaParams p, int lyr) {
  const float* bias = p.bff2 + lyr * kD;
  const float* gam = p.ln2g + lyr * kD;
  const float* bet = p.ln2b + lyr * kD;
  const int w = threadIdx.x >> 6, l = threadIdx.x & 63;
  const int row = blockIdx.x * 4 + w;
  f32x4 v = *(const f32x4*)(p.xf + (size_t)row * kD + l * 4);
  f32x4 b4 = *(const f32x4*)(bias + l * 4);
  #pragma unroll
  for (int i = 0; i < 4; i++) v[i] += b4[i];
  #pragma unroll
  for (int s = 0; s < 4; s++) {
    f32x4 t = *(const f32x4*)(p.pf + ((size_t)s * kSEQ + row) * kD + l * 4);
    #pragma unroll
    for (int i = 0; i < 4; i++) v[i] += t[i];
  }
  float su = v[0] + v[1] + v[2] + v[3];
  #pragma unroll
  for (int mm = 1; mm < 64; mm <<= 1) su += __shfl_xor(su, mm);
  const float mn = su * (1.0f / 256.0f);
  const float d0 = v[0] - mn, d1 = v[1] - mn, d2 = v[2] - mn, d3 = v[3] - mn;
  float s2 = d0 * d0 + d1 * d1 + d2 * d2 + d3 * d3;
  #pragma unroll
  for (int mm = 1; mm < 64; mm <<= 1) s2 += __shfl_xor(s2, mm);
  const float rstd = rsqrtf(s2 * (1.0f / 256.0f) + 1e-5f);
  f32x4 g4 = *(const f32x4*)(gam + l * 4);
  f32x4 be4 = *(const f32x4*)(bet + l * 4);
  f32x4 y;
  y[0] = d0 * rstd * g4[0] + be4[0];
  y[1] = d1 * rstd * g4[1] + be4[1];
  y[2] = d2 * rstd * g4[2] + be4[2];
  y[3] = d3 * rstd * g4[3] + be4[3];
  *(f32x4*)(p.xf + (size_t)row * kD + l * 4) = y;
  unsigned long long pk = (unsigned long long)f2b(y[0]) |
                          ((unsigned long long)f2b(y[1]) << 16) |
                          ((unsigned long long)f2b(y[2]) << 32) |
                          ((unsigned long long)f2b(y[3]) << 48);
  *(unsigned long long*)(p.xb + (size_t)row * kD + l * 4) = pk;
}

// ---------------------------------------------------------------- heads
__global__ __launch_bounds__(256) void k_h1(MegaParams p) {
  __shared__ float tl[256];
  __shared__ float red[4][64];
  const int tid = threadIdx.x;
  tl[tid] = p.xf[tid];
  __syncthreads();
  const int jj = blockIdx.x * 64;
  const bool actor = jj < 512;
  const float* W = actor ? p.aW1 : p.cW1;
  const float* b = actor ? p.ab1 : p.cb1;
  const int j0 = actor ? jj : jj - 512;
  const int ks = tid >> 6, j = tid & 63;
  float s = 0.f;
  #pragma unroll 4
  for (int k2 = ks * 64; k2 < ks * 64 + 64; k2++)
    s += tl[k2] * W[(size_t)k2 * 512 + j0 + j];
  red[ks][j] = s;
  __syncthreads();
  if (tid < 64) {
    float t = red[0][tid] + red[1][tid] + red[2][tid] + red[3][tid] + b[j0 + tid];
    p.h1[jj + tid] = tanhf(t);
  }
}

__global__ __launch_bounds__(256) void k_h2(MegaParams p) {
  __shared__ float tl[512];
  __shared__ float red[4][64];
  const int tid = threadIdx.x;
  const int jj = blockIdx.x * 64;
  const bool actor = jj < 512;
  const float* hin = actor ? p.h1 : p.h1 + 512;
  tl[tid] = hin[tid];
  tl[tid + 256] = hin[tid + 256];
  __syncthreads();
  const float* W = actor ? p.aW2 : p.cW2;
  const float* b = actor ? p.ab2 : p.cb2;
  const int j0 = actor ? jj : jj - 512;
  const int ks = tid >> 6, j = tid & 63;
  float s = 0.f;
  #pragma unroll 4
  for (int k2 = ks * 128; k2 < ks * 128 + 128; k2++)
    s += tl[k2] * W[(size_t)k2 * 512 + j0 + j];
  red[ks][j] = s;
  __syncthreads();
  if (tid < 64) {
    float t = red[0][tid] + red[1][tid] + red[2][tid] + red[3][tid] + b[j0 + tid];
    p.h2[jj + tid] = tanhf(t);
  }
}

__global__ __launch_bounds__(256) void k_h3(MegaParams p) {
  __shared__ float ha[512], hc[512], vred[4];
  const int tid = threadIdx.x;
  ha[tid] = p.h2[tid];
  ha[tid + 256] = p.h2[tid + 256];
  hc[tid] = p.h2[512 + tid];
  hc[tid + 256] = p.h2[768 + tid];
  __syncthreads();
  const int g = tid >> 4, l16 = tid & 15;
  float s = 0.f;
  for (int k2 = l16 * 32; k2 < l16 * 32 + 32; k2++)
    s += ha[k2] * p.aWo[(size_t)k2 * kA + g];
  #pragma unroll
  for (int mm = 1; mm <= 8; mm <<= 1) s += __shfl_xor(s, mm);
  if (l16 == 0) p.out[1 + g] = s + p.abo[g];
  float vv = hc[tid] * p.cWo[tid] + hc[tid + 256] * p.cWo[tid + 256];
  #pragma unroll
  for (int mm = 1; mm <= 32; mm <<= 1) vv += __shfl_xor(vv, mm);
  if ((tid & 63) == 0) vred[tid >> 6] = vv;
  __syncthreads();
  if (tid == 0)
    p.out[0] = vred[0] + vred[1] + vred[2] + vred[3] + p.cbo[0];
  p.out[17 + tid] = tanhf(p.obs[tid]);
}

// ---------------------------------------------------------------- launch
extern "C" void kernel_launch(void* const* d_in, const int* in_sizes, int n_in,
                              void* d_out, int out_size, void* d_ws, size_t ws_size,
                              hipStream_t stream) {
  const float* obs   = (const float*)d_in[0];
  const float* oldv  = (const float*)d_in[1];
  const float* Wcore = (const float*)d_in[2];
  const float* bcore = (const float*)d_in[3];
  const float* Wmemo = (const float*)d_in[4];
  const float* bmemo = (const float*)d_in[5];
  const float* Wq    = (const float*)d_in[6];
  const float* bq    = (const float*)d_in[7];
  const float* Wk    = (const float*)d_in[8];
  const float* bk    = (const float*)d_in[9];
  const float* Wv    = (const float*)d_in[10];
  const float* bv    = (const float*)d_in[11];
  const float* Wo    = (const float*)d_in[12];
  const float* bo    = (const float*)d_in[13];
  const float* ln1g  = (const float*)d_in[14];
  const float* ln1b  = (const float*)d_in[15];
  const float* ln2g  = (const float*)d_in[16];
  const float* ln2b  = (const float*)d_in[17];
  const float* Wff1  = (const float*)d_in[18];
  const float* bff1  = (const float*)d_in[19];
  const float* Wff2  = (const float*)d_in[20];
  const float* bff2  = (const float*)d_in[21];

  MegaParams P;
  P.obs = obs; P.oldv = oldv; P.Wcore = Wcore; P.bcore = bcore;
  P.Wmemo0 = Wmemo; P.bmemo = bmemo; P.Wmemo2 = Wmemo + 256 * 256;
  P.bq = bq; P.bk = bk; P.bv = bv; P.bo = bo;
  P.ln1g = ln1g; P.ln1b = ln1b; P.ln2g = ln2g; P.ln2b = ln2b;
  P.bff1 = bff1; P.bff2 = bff2;
  P.aW1 = (const float*)d_in[22]; P.ab1 = (const float*)d_in[23];
  P.aW2 = (const float*)d_in[24]; P.ab2 = (const float*)d_in[25];
  P.aWo = (const float*)d_in[26]; P.abo = (const float*)d_in[27];
  P.cW1 = (const float*)d_in[28]; P.cb1 = (const float*)d_in[29];
  P.cW2 = (const float*)d_in[30]; P.cb2 = (const float*)d_in[31];
  P.cWo = (const float*)d_in[32]; P.cbo = (const float*)d_in[33];

  char* ws = (char*)d_ws;
  P.xf = (float*)(ws + 0);                           // 2 MB
  P.xb = (unsigned short*)(ws + (2u << 20));         // 1 MB
  P.qb = (unsigned short*)(ws + (3u << 20));         // 1 MB
  P.kb = (unsigned short*)(ws + (4u << 20));         // 1 MB
  P.vb = (unsigned short*)(ws + (5u << 20));         // 1 MB
  P.hb = (unsigned short*)(ws + (6u << 20));         // 4 MB
  P.wT = (unsigned short*)(ws + (10u << 20));        // ~3 MB
  P.out = (float*)d_out;

  int nsplit = 8;
  const size_t paccOff = (size_t)14u << 20;
  const size_t pmlOff  = (size_t)31u << 20;
  const size_t pfOff   = (size_t)33u << 20;
  while (nsplit > 1 &&
         (paccOff + (size_t)nsplit * 8 * kSEQ * kHD * 4 > pmlOff ||
          pfOff + (size_t)4 * kSEQ * kD * 4 + 16384 > ws_size))
    nsplit >>= 1;
  P.pacc = (float*)(ws + paccOff);
  P.pml  = (float*)(ws + pmlOff);
  P.pf   = (float*)(ws + pfOff);
  P.h1 = (float*)(ws + pfOff + (size_t)4 * kSEQ * kD * 4);
  P.h2 = P.h1 + 1024;
  P.nsplit = nsplit;
  P.tpb = 32 / nsplit;

  int cur = 0;
  for (int l2 = 0; l2 < 2; l2++) {
    P.oQKV[l2] = cur; cur += 196608;
    P.oWoT[l2] = cur; cur += 65536;
    P.oFF1[l2] = cur; cur += 262144;
    P.oFF2[l2] = cur; cur += 262144;
  }

  int idx = 0, ts = 0;
  auto add = [&](const float* s, int K, int N, int dst) {
    P.tab.src[idx] = s; P.tab.K[idx] = K; P.tab.N[idx] = N;
    P.tab.dst[idx] = dst; P.tab.tstart[idx] = ts;
    ts += (K >> 6) * (N >> 6); idx++;
  };
  for (int l2 = 0; l2 < 2; l2++) {
    add(Wq + l2 * 65536, 256, 256, P.oQKV[l2]);
    add(Wk + l2 * 65536, 256, 256, P.oQKV[l2] + 65536);
    add(Wv + l2 * 65536, 256, 256, P.oQKV[l2] + 131072);
    add(Wo + l2 * 65536, 256, 256, P.oWoT[l2]);
    add(Wff1 + l2 * 262144, 256, 1024, P.oFF1[l2]);
    add(Wff2 + l2 * 262144, 1024, 256, P.oFF2[l2]);
  }
  P.tab.tstart[idx] = ts;
  P.convJobs = ts;

  k_cvm<<<256 + ts + 1, 256, 0, stream>>>(P);
  for (int lyr = 0; lyr < 2; lyr++) {
    k_qkv<<<768, 256, 0, stream>>>(P, lyr);
    k_attn<<<256 * nsplit, 256, 0, stream>>>(P);
    k_woln<<<128, 256, 0, stream>>>(P, lyr);
    k_ff1<<<1024, 256, 0, stream>>>(P, lyr);
    k_ff2p<<<1024, 256, 0, stream>>>(P, lyr);
    k_ln2r<<<512, 256, 0, stream>>>(P, lyr);
  }
  k_h1<<<16, 256, 0, stream>>>(P);
  k_h2<<<16, 256, 0, stream>>>(P);
  k_h3<<<1, 256, 0, stream>>>(P);
}